// Round 4
// baseline (602.216 us; speedup 1.0000x reference)
//
#include <hip/hip_runtime.h>
#include <math.h>

#define B_  32
#define N_  1024
#define D_  512
#define M_  1023          // n-1
#define GR_ 1022          // gate rows = n-2
#define R_  (B_*M_)       // 32736 doc rows (mean denominator)

// clang ext vector: accepted by __builtin_nontemporal_load (HIP_vector_type is not)
typedef float f4 __attribute__((ext_vector_type(4)));

// ws layout (bytes):
//   0      : double accum[2]               (zeroed)
//   64     : csf   [B_*M_] floats (131072 resv, zeroed)  colsum fwd
//   131136 : csb   [B_*M_] floats (zeroed)                colsum bwd
//   262208 : uf    [B_*D_] floats (65536)
//   327744 : ub    [B_*D_] floats (65536)
//   393280 : diagf [B_*M_] floats (131072 resv)  gate_fwd[j-1,j], j>=1
//   524352 : diagb [B_*M_] floats (131072 resv)
//   total 655424 B

__device__ __forceinline__ float d4(f4 a, f4 b) {
    return a.x * b.x + a.y * b.y + a.z * b.z + a.w * b.w;
}

// ---------------- K1: per-batch u-vectors  uf = rep[b,0,:]^T W, ub = rep[b,1023,:]^T W
__global__ __launch_bounds__(256) void k_uvec(const float* __restrict__ rep,
                                              const float* __restrict__ W,
                                              float* __restrict__ uf,
                                              float* __restrict__ ub) {
    int b = blockIdx.y;
    int e = blockIdx.x * 256 + threadIdx.x;          // column of W, 0..511
    __shared__ float r0[D_], r1[D_];
    const float* repb = rep + (size_t)b * N_ * D_;
    for (int d = threadIdx.x; d < D_; d += 256) {
        r0[d] = repb[d];
        r1[d] = repb[(size_t)(N_ - 1) * D_ + d];
    }
    __syncthreads();
    float sf = 0.f, sb = 0.f;
#pragma unroll 8
    for (int d = 0; d < D_; ++d) {
        float w = W[d * D_ + e];                     // coalesced across e
        sf += r0[d] * w;
        sb += r1[d] * w;
    }
    uf[b * D_ + e] = sf;
    ub[b * D_ + e] = sb;
}

// ---------------- K2: triangular column sums cs[b,j] = sum_{t<j} gate[b,t,j],
//                  and diag capture diag[b,j] = gate[b,j-1,j] (block owning t=j-1 writes)
__global__ __launch_bounds__(256) void k_colsum(const float* __restrict__ gf,
                                                const float* __restrict__ gb,
                                                float* __restrict__ csf,
                                                float* __restrict__ csb,
                                                float* __restrict__ diagf,
                                                float* __restrict__ diagb) {
    int b  = blockIdx.z;
    int j  = blockIdx.x * 256 + threadIdx.x;
    int t0 = blockIdx.y * 128;
    if (j >= M_) return;
    int tend = min(min(t0 + 128, GR_), j);           // only t < j contributes
    const float* gfb = gf + (size_t)b * GR_ * M_;
    const float* gbb = gb + (size_t)b * GR_ * M_;
    float sf = 0.f, sb = 0.f;
#pragma unroll 4
    for (int t = t0; t < tend; ++t) {                // coalesced across j; single-use -> nt
        sf += __builtin_nontemporal_load(&gfb[(size_t)t * M_ + j]);
        sb += __builtin_nontemporal_load(&gbb[(size_t)t * M_ + j]);
    }
    if (t0 < j) {
        atomicAdd(&csf[b * M_ + j], sf);
        atomicAdd(&csb[b * M_ + j], sb);
    }
    // exactly one y-block covers t = j-1 (it is >= t0 and < min(t0+128, GR_))
    if (j >= 1 && (j - 1) >= t0 && (j - 1) < t0 + 128) {
        diagf[b * M_ + j] = gfb[(size_t)(j - 1) * M_ + j];   // L1-hot reload
        diagb[b * M_ + j] = gbb[(size_t)(j - 1) * M_ + j];
    }
}

// ---------------- K3: wave per (b, rep-row t); rep row serves fwd doc j=t-1 and bwd doc j=1022-t
// fixed geometry: 2048 blocks x 256 thr = 8192 waves; b = wid&31, t strides by 256
__global__ __launch_bounds__(256) void k_main(const float* __restrict__ rep,
                                              const float* __restrict__ fneg,
                                              const float* __restrict__ bneg,
                                              const float* __restrict__ uf,
                                              const float* __restrict__ ub,
                                              const float* __restrict__ csf,
                                              const float* __restrict__ csb,
                                              const float* __restrict__ diagf,
                                              const float* __restrict__ diagb,
                                              const float* __restrict__ bias,
                                              double* __restrict__ accum) {
    const float inv = 0.04419417382415922f;          // 1/sqrt(512)
    int gtid = blockIdx.x * blockDim.x + threadIdx.x;
    int wid  = gtid >> 6;
    int lane = threadIdx.x & 63;
    int b    = wid & 31;                             // fixed batch per wave
    int tA   = wid >> 5;                             // 0..255
    float bv = bias[0];

    const f4* ufb = (const f4*)(uf + b * D_);
    const f4* ubb = (const f4*)(ub + b * D_);
    f4 u0 = ufb[lane], u1 = ufb[lane + 64];          // hoisted: loaded once per wave
    f4 v0 = ubb[lane], v1 = ubb[lane + 64];

    double ps = 0.0, ns = 0.0;
    for (int t = tA; t < N_; t += 256) {
        const f4* rrow = (const f4*)(rep + ((size_t)b * N_ + t) * D_);
        f4 r0 = __builtin_nontemporal_load(&rrow[lane]);
        f4 r1 = __builtin_nontemporal_load(&rrow[lane + 64]);

        float dfp = d4(u0, r0) + d4(u1, r1);         // fwd-pos dot (doc j = t-1)
        float dbp = d4(v0, r0) + d4(v1, r1);         // bwd-pos dot (doc j = 1022-t)
        float dfn = 0.f, dbn = 0.f;
        bool hasF = (t >= 1);                        // wave-uniform (t uniform per wave)
        bool hasB = (t <= N_ - 2);
        if (hasF) {
            const f4* fr = (const f4*)(fneg + ((size_t)b * M_ + (t - 1)) * D_);
            f4 e0 = __builtin_nontemporal_load(&fr[lane]);
            f4 e1 = __builtin_nontemporal_load(&fr[lane + 64]);
            dfn = d4(u0, e0) + d4(u1, e1);
        }
        if (hasB) {
            const f4* br = (const f4*)(bneg + ((size_t)b * M_ + (N_ - 2 - t)) * D_);
            f4 g0 = __builtin_nontemporal_load(&br[lane]);
            f4 g1 = __builtin_nontemporal_load(&br[lane + 64]);
            dbn = d4(v0, g0) + d4(v1, g1);
        }
#pragma unroll
        for (int o = 32; o > 0; o >>= 1) {           // 64-lane butterfly, 4 values
            dfp += __shfl_xor(dfp, o);
            dfn += __shfl_xor(dfn, o);
            dbp += __shfl_xor(dbp, o);
            dbn += __shfl_xor(dbn, o);
        }
        if (hasF) {
            int j = t - 1;
            float diag = (j == 0) ? 1.f : diagf[b * M_ + j];
            float cf = diag * (1.f + csf[b * M_ + j]);
            float lp = (cf * dfp + bv) * inv;
            float ln = (cf * dfn + bv) * inv;
            // stable log_sigmoid(x) = min(x,0) - log1p(exp(-|x|))
            ps += (double)(fminf(lp, 0.f)  - log1pf(expf(-fabsf(lp))));
            ns += (double)(fminf(-ln, 0.f) - log1pf(expf(-fabsf(ln))));
        }
        if (hasB) {
            int j = N_ - 2 - t;
            float diag = (j == 0) ? 1.f : diagb[b * M_ + j];
            float cb = diag * (1.f + csb[b * M_ + j]);
            float lp = (cb * dbp + bv) * inv;
            float ln = (cb * dbn + bv) * inv;
            ps += (double)(fminf(lp, 0.f)  - log1pf(expf(-fabsf(lp))));
            ns += (double)(fminf(-ln, 0.f) - log1pf(expf(-fabsf(ln))));
        }
    }
    if (lane == 0) {                                 // 0.5: mean((fp+bp)/2)
        atomicAdd(&accum[0], 0.5 * ps);
        atomicAdd(&accum[1], 0.5 * ns);
    }
}

// ---------------- K4: finalize means over B*m = 32736 rows
__global__ void k_final(const double* __restrict__ accum, float* __restrict__ out) {
    if (threadIdx.x == 0) {
        out[0] = (float)(accum[0] / (double)R_);
        out[1] = (float)(accum[1] / (double)R_);
    }
}

extern "C" void kernel_launch(void* const* d_in, const int* in_sizes, int n_in,
                              void* d_out, int out_size, void* d_ws, size_t ws_size,
                              hipStream_t stream) {
    const float* rep  = (const float*)d_in[0];
    const float* gf   = (const float*)d_in[1];
    const float* gb   = (const float*)d_in[2];
    const float* fneg = (const float*)d_in[3];
    const float* bneg = (const float*)d_in[4];
    const float* W    = (const float*)d_in[5];
    const float* bias = (const float*)d_in[6];
    float* out = (float*)d_out;

    char* ws = (char*)d_ws;
    double* accum = (double*)ws;
    float* csf   = (float*)(ws + 64);
    float* csb   = (float*)(ws + 64 + 131072);
    float* uf    = (float*)(ws + 64 + 262144);
    float* ub    = (float*)(ws + 64 + 327680);
    float* diagf = (float*)(ws + 64 + 393216);
    float* diagb = (float*)(ws + 64 + 524288);

    // zero accum + colsum buffers (ws re-poisoned to 0xAA before every launch)
    (void)hipMemsetAsync(ws, 0, 64 + 262144, stream);

    k_uvec  <<<dim3(2, B_),    256, 0, stream>>>(rep, W, uf, ub);
    k_colsum<<<dim3(4, 8, B_), 256, 0, stream>>>(gf, gb, csf, csb, diagf, diagb);
    k_main  <<<2048,           256, 0, stream>>>(rep, fneg, bneg,
                                                 uf, ub, csf, csb, diagf, diagb, bias, accum);
    k_final <<<1, 64, 0, stream>>>(accum, out);
}

// Round 5
// 441.200 us; speedup vs baseline: 1.3649x; 1.3649x over previous
//
#include <hip/hip_runtime.h>
#include <math.h>

#define B_  32
#define N_  1024
#define D_  512
#define M_  1023          // n-1
#define GR_ 1022          // gate rows = n-2
#define R_  (B_*M_)       // 32736 doc rows (mean denominator)
#define P_  1024          // padded row stride for [b][j] ws arrays
#define TC_ 8             // t-chunks in colsum
#define TCH_ 128          // t-chunk height
#define NBLK_MAIN 2048

// clang ext vector: accepted by __builtin_nontemporal_load (HIP_vector_type is not)
typedef float f4 __attribute__((ext_vector_type(4)));

__device__ __forceinline__ float d4(f4 a, f4 b) {
    return a.x * b.x + a.y * b.y + a.z * b.z + a.w * b.w;
}

// ws layout (bytes), every element written each launch -> no memset needed:
//   0        part_f [TC_][B_][P_] f32   1048576
//   1048576  part_b [TC_][B_][P_] f32   1048576
//   2097152  diagf  [B_][P_] f32         131072   gate_fwd[j-1,j] (j>=1)
//   2228224  diagb  [B_][P_] f32         131072
//   2359296  cf     [B_][P_] f32         131072   diag*(1+colsum), fwd
//   2490368  cb     [B_][P_] f32         131072
//   2621440  uf     [B_][D_] f32          65536
//   2686976  ub     [B_][D_] f32          65536
//   2752512  pblk   [NBLK_MAIN] f64       16384
//   2768896  nblk   [NBLK_MAIN] f64       16384
//   total 2785280 B

// ---------------- K1: per-batch u-vectors  uf = rep[b,0,:]^T W, ub = rep[b,1023,:]^T W
__global__ __launch_bounds__(256) void k_uvec(const float* __restrict__ rep,
                                              const float* __restrict__ W,
                                              float* __restrict__ uf,
                                              float* __restrict__ ub) {
    int b = blockIdx.y;
    int e = blockIdx.x * 256 + threadIdx.x;          // column of W, 0..511
    __shared__ float r0[D_], r1[D_];
    const float* repb = rep + (size_t)b * N_ * D_;
    for (int d = threadIdx.x; d < D_; d += 256) {
        r0[d] = repb[d];
        r1[d] = repb[(size_t)(N_ - 1) * D_ + d];
    }
    __syncthreads();
    float sf = 0.f, sb = 0.f;
#pragma unroll 8
    for (int d = 0; d < D_; ++d) {
        float w = W[d * D_ + e];                     // coalesced across e
        sf += r0[d] * w;
        sb += r1[d] * w;
    }
    uf[b * D_ + e] = sf;
    ub[b * D_ + e] = sb;
}

// ---------------- K2: per-chunk triangular column sums (NO atomics; one writer per slot)
// partial[tc][b][j] = sum over t in [tc*128, tc*128+128) ∩ [0, j) of gate[b,t,j]
__global__ __launch_bounds__(256) void k_colsum(const float* __restrict__ gf,
                                                const float* __restrict__ gb,
                                                float* __restrict__ part_f,
                                                float* __restrict__ part_b,
                                                float* __restrict__ diagf,
                                                float* __restrict__ diagb) {
    int b  = blockIdx.z;
    int tc = blockIdx.y;
    int j  = blockIdx.x * 256 + threadIdx.x;         // 0..1023
    if (j >= M_) return;
    int t0 = tc * TCH_;
    int tend = min(min(t0 + TCH_, GR_), j);
    const float* gfb = gf + (size_t)b * GR_ * M_;
    const float* gbb = gb + (size_t)b * GR_ * M_;
    float sf = 0.f, sb = 0.f;
#pragma unroll 4
    for (int t = t0; t < tend; ++t) {                // coalesced across j; single-use -> nt
        sf += __builtin_nontemporal_load(&gfb[(size_t)t * M_ + j]);
        sb += __builtin_nontemporal_load(&gbb[(size_t)t * M_ + j]);
    }
    int slot = (tc * B_ + b) * P_ + j;
    part_f[slot] = sf;                               // unconditional (0 if empty range)
    part_b[slot] = sb;
    // exactly one tc covers t = j-1 (always < GR_ since j <= 1022)
    if (j >= 1 && (unsigned)(j - 1 - t0) < TCH_) {
        diagf[b * P_ + j] = gfb[(size_t)(j - 1) * M_ + j];   // L1-hot reload
        diagb[b * P_ + j] = gbb[(size_t)(j - 1) * M_ + j];
    }
}

// ---------------- K2b: reduce 8 partials, fold diag -> per-row coefficient c = diag*(1+sum)
__global__ __launch_bounds__(256) void k_csred(const float* __restrict__ part_f,
                                               const float* __restrict__ part_b,
                                               const float* __restrict__ diagf,
                                               const float* __restrict__ diagb,
                                               float* __restrict__ cf,
                                               float* __restrict__ cb) {
    int idx = blockIdx.x * 256 + threadIdx.x;        // 0 .. B_*P_-1
    int b = idx >> 10, j = idx & (P_ - 1);
    if (j >= M_) return;
    float sf = 0.f, sb = 0.f;
#pragma unroll
    for (int tc = 0; tc < TC_; ++tc) {
        sf += part_f[(tc * B_ + b) * P_ + j];
        sb += part_b[(tc * B_ + b) * P_ + j];
    }
    float df = (j == 0) ? 1.f : diagf[b * P_ + j];
    float db = (j == 0) ? 1.f : diagb[b * P_ + j];
    cf[b * P_ + j] = df * (1.f + sf);
    cb[b * P_ + j] = db * (1.f + sb);
}

// ---------------- K3: wave per (b, rep-row t); rep row serves fwd doc j=t-1 and bwd doc j=1022-t
// 2048 blocks x 256 thr = 8192 waves; b = wid&31, t strides by 256. Block-level partials, NO atomics.
__global__ __launch_bounds__(256) void k_main(const float* __restrict__ rep,
                                              const float* __restrict__ fneg,
                                              const float* __restrict__ bneg,
                                              const float* __restrict__ uf,
                                              const float* __restrict__ ub,
                                              const float* __restrict__ cf,
                                              const float* __restrict__ cb,
                                              const float* __restrict__ bias,
                                              double* __restrict__ pblk,
                                              double* __restrict__ nblk) {
    const float inv = 0.04419417382415922f;          // 1/sqrt(512)
    int gtid = blockIdx.x * blockDim.x + threadIdx.x;
    int wid  = gtid >> 6;
    int lane = threadIdx.x & 63;
    int wslot = threadIdx.x >> 6;                    // 0..3
    int b    = wid & 31;                             // fixed batch per wave
    int tA   = wid >> 5;                             // 0..255
    float bv = bias[0];

    const f4* ufb = (const f4*)(uf + b * D_);
    const f4* ubb = (const f4*)(ub + b * D_);
    f4 u0 = ufb[lane], u1 = ufb[lane + 64];          // hoisted: loaded once per wave
    f4 v0 = ubb[lane], v1 = ubb[lane + 64];

    double ps = 0.0, ns = 0.0;
    for (int t = tA; t < N_; t += 256) {
        const f4* rrow = (const f4*)(rep + ((size_t)b * N_ + t) * D_);
        f4 r0 = __builtin_nontemporal_load(&rrow[lane]);
        f4 r1 = __builtin_nontemporal_load(&rrow[lane + 64]);

        float dfp = d4(u0, r0) + d4(u1, r1);         // fwd-pos dot (doc j = t-1)
        float dbp = d4(v0, r0) + d4(v1, r1);         // bwd-pos dot (doc j = 1022-t)
        float dfn = 0.f, dbn = 0.f;
        bool hasF = (t >= 1);                        // wave-uniform (t uniform per wave)
        bool hasB = (t <= N_ - 2);
        if (hasF) {
            const f4* fr = (const f4*)(fneg + ((size_t)b * M_ + (t - 1)) * D_);
            f4 e0 = __builtin_nontemporal_load(&fr[lane]);
            f4 e1 = __builtin_nontemporal_load(&fr[lane + 64]);
            dfn = d4(u0, e0) + d4(u1, e1);
        }
        if (hasB) {
            const f4* br = (const f4*)(bneg + ((size_t)b * M_ + (N_ - 2 - t)) * D_);
            f4 g0 = __builtin_nontemporal_load(&br[lane]);
            f4 g1 = __builtin_nontemporal_load(&br[lane + 64]);
            dbn = d4(v0, g0) + d4(v1, g1);
        }
#pragma unroll
        for (int o = 32; o > 0; o >>= 1) {           // 64-lane butterfly, 4 values
            dfp += __shfl_xor(dfp, o);
            dfn += __shfl_xor(dfn, o);
            dbp += __shfl_xor(dbp, o);
            dbn += __shfl_xor(dbn, o);
        }
        if (hasF) {
            int j = t - 1;
            float c = cf[b * P_ + j];
            float lp = (c * dfp + bv) * inv;
            float ln = (c * dfn + bv) * inv;
            // stable log_sigmoid(x) = min(x,0) - log1p(exp(-|x|))
            ps += (double)(fminf(lp, 0.f)  - log1pf(expf(-fabsf(lp))));
            ns += (double)(fminf(-ln, 0.f) - log1pf(expf(-fabsf(ln))));
        }
        if (hasB) {
            int j = N_ - 2 - t;
            float c = cb[b * P_ + j];
            float lp = (c * dbp + bv) * inv;
            float ln = (c * dbn + bv) * inv;
            ps += (double)(fminf(lp, 0.f)  - log1pf(expf(-fabsf(lp))));
            ns += (double)(fminf(-ln, 0.f) - log1pf(expf(-fabsf(ln))));
        }
    }
    // block reduction (4 waves) -> one plain store per block
    __shared__ double red[4][2];
    if (lane == 0) { red[wslot][0] = ps; red[wslot][1] = ns; }
    __syncthreads();
    if (threadIdx.x == 0) {
        pblk[blockIdx.x] = red[0][0] + red[1][0] + red[2][0] + red[3][0];
        nblk[blockIdx.x] = red[0][1] + red[1][1] + red[2][1] + red[3][1];
    }
}

// ---------------- K4: reduce 2048 block partials; means over B*m rows, /2 pairing factor
__global__ __launch_bounds__(256) void k_final(const double* __restrict__ pblk,
                                               const double* __restrict__ nblk,
                                               float* __restrict__ out) {
    int tid = threadIdx.x, lane = tid & 63, w = tid >> 6;
    double p = 0.0, n = 0.0;
    for (int i = tid; i < NBLK_MAIN; i += 256) { p += pblk[i]; n += nblk[i]; }
#pragma unroll
    for (int o = 32; o > 0; o >>= 1) { p += __shfl_xor(p, o); n += __shfl_xor(n, o); }
    __shared__ double sp[4], sn[4];
    if (lane == 0) { sp[w] = p; sn[w] = n; }
    __syncthreads();
    if (tid == 0) {
        double P = sp[0] + sp[1] + sp[2] + sp[3];
        double Nn = sn[0] + sn[1] + sn[2] + sn[3];
        out[0] = (float)(P / (2.0 * (double)R_));
        out[1] = (float)(Nn / (2.0 * (double)R_));
    }
}

extern "C" void kernel_launch(void* const* d_in, const int* in_sizes, int n_in,
                              void* d_out, int out_size, void* d_ws, size_t ws_size,
                              hipStream_t stream) {
    const float* rep  = (const float*)d_in[0];
    const float* gf   = (const float*)d_in[1];
    const float* gb   = (const float*)d_in[2];
    const float* fneg = (const float*)d_in[3];
    const float* bneg = (const float*)d_in[4];
    const float* W    = (const float*)d_in[5];
    const float* bias = (const float*)d_in[6];
    float* out = (float*)d_out;

    char* ws = (char*)d_ws;
    float*  part_f = (float*)(ws);
    float*  part_b = (float*)(ws + 1048576);
    float*  diagf  = (float*)(ws + 2097152);
    float*  diagb  = (float*)(ws + 2228224);
    float*  cf     = (float*)(ws + 2359296);
    float*  cb     = (float*)(ws + 2490368);
    float*  uf     = (float*)(ws + 2621440);
    float*  ub     = (float*)(ws + 2686976);
    double* pblk   = (double*)(ws + 2752512);
    double* nblk   = (double*)(ws + 2768896);

    k_uvec  <<<dim3(2, B_),       256, 0, stream>>>(rep, W, uf, ub);
    k_colsum<<<dim3(4, TC_, B_),  256, 0, stream>>>(gf, gb, part_f, part_b, diagf, diagb);
    k_csred <<<128,               256, 0, stream>>>(part_f, part_b, diagf, diagb, cf, cb);
    k_main  <<<NBLK_MAIN,         256, 0, stream>>>(rep, fneg, bneg, uf, ub, cf, cb,
                                                    bias, pblk, nblk);
    k_final <<<1,                 256, 0, stream>>>(pblk, nblk, out);
}